// Round 6
// baseline (71951.904 us; speedup 1.0000x reference)
//
#include <hip/hip_runtime.h>
#include <stdint.h>

#define T_STEPS 16384
#define NDIM 256
#define MDIM 512
#define KP1 512
#define LOUT 256
#define G 16
#define TPB 256

typedef unsigned long long u64;
typedef unsigned int u32;

// ---- ws layout (float offsets) ----
constexpr size_t OFF_GH    = 0;                         // [512][1536] cached W_hh@M[q]+b_hh
constexpr size_t OFF_GHS   = 512ull * 1536;             // [1536] scratch gh (q==0 / startup)
constexpr size_t OFF_M     = OFF_GHS + 1536;            // [512][512] memory rows
constexpr size_t OFF_RING  = OFF_M + 512ull * 512;      // [4][1536] gi ring
constexpr size_t OFF_H     = OFF_RING + 4ull * 1536;    // [16384][512] hidden outputs
constexpr size_t OFF_VWT   = OFF_H + 16384ull * 512;    // [512][256] V_w transposed
constexpr size_t OFF_FLAGS = OFF_VWT + 512ull * 256;    // u64 flags (compact layout)

__device__ __forceinline__ float ld_cohf(const float* p) {
  return __hip_atomic_load(p, __ATOMIC_RELAXED, __HIP_MEMORY_SCOPE_AGENT);
}
__device__ __forceinline__ void st_cohf(float* p, float v) {
  __hip_atomic_store(p, v, __ATOMIC_RELAXED, __HIP_MEMORY_SCOPE_AGENT);
}
__device__ __forceinline__ u64 ld_flag(const u64* p) {
  return __hip_atomic_load(p, __ATOMIC_RELAXED, __HIP_MEMORY_SCOPE_AGENT);
}
__device__ __forceinline__ void st_flag_rel(u64* p, u64 v) {
  __hip_atomic_store(p, v, __ATOMIC_RELEASE, __HIP_MEMORY_SCOPE_AGENT);
}
__device__ __forceinline__ void st_flag_rlx(u64* p, u64 v) {
  __hip_atomic_store(p, v, __ATOMIC_RELAXED, __HIP_MEMORY_SCOPE_AGENT);
}

__device__ __forceinline__ float sigm(float x) {
  return __builtin_amdgcn_rcpf(1.0f + __expf(-x));
}
__device__ __forceinline__ float tanh_(float x) {
  return 1.0f - 2.0f * __builtin_amdgcn_rcpf(__expf(2.0f * x) + 1.0f);
}

__global__ __launch_bounds__(TPB, 2) void dmm_main(
    const float* __restrict__ X, const float* __restrict__ h0,
    const float* __restrict__ W_ih, const float* __restrict__ W_hh,
    const float* __restrict__ b_ih, const float* __restrict__ b_hh,
    const float* __restrict__ C_w, const float* __restrict__ C_b,
    float* __restrict__ ws)
{
  const int b   = blockIdx.x;
  const int tid = threadIdx.x;
  const int w   = tid >> 6;
  const int l   = tid & 63;

  float* GH   = ws + OFF_GH;
  float* GHS  = ws + OFF_GHS;
  float* Mrow = ws + OFF_M;
  float* RING = ws + OFF_RING;
  float* H    = ws + OFF_H;
  u64*   F    = (u64*)(ws + OFF_FLAGS);
  // flagS = F[0..15], flagB = F[16 + p*16 + b], flagC = F[48 + p*16 + b]

  __shared__ __align__(16) float hnew[MDIM];
  __shared__ __align__(16) float red[96 * 36];      // logits reduce + gh reduce (rare path)
  __shared__ __align__(16) float red2[2][96 * 20];  // gi reduce, double-buffered by s&1
  __shared__ u32 written[KP1];
  __shared__ u32 bc[4];

  // ---- persistent register-resident weight slices ----
  float wih[6][16];
  {
    int rbase = 96 * b + w * 24 + (l >> 4) * 6;
    int cbase = 16 * (l & 15);
#pragma unroll
    for (int i = 0; i < 6; i++)
#pragma unroll
      for (int k = 0; k < 16; k++)
        wih[i][k] = W_ih[(rbase + i) * NDIM + cbase + k];
  }
  float cw[4][16];
  {
    int rbase = 32 * b + w * 8 + (l >> 5) * 4;
    int cbase = 16 * (l & 31);
#pragma unroll
    for (int i = 0; i < 4; i++)
#pragma unroll
      for (int k = 0; k < 16; k++)
        cw[i][k] = C_w[(rbase + i) * MDIM + cbase + k];
  }

  for (int i = tid; i < KP1; i += TPB) written[i] = 0u;
  hnew[tid]       = h0[tid];
  hnew[tid + 256] = h0[tid + 256];
  __syncthreads();

  // ---- produce gi(s) = W_ih@x_s + b_ih into RING ----
  // parity-double-buffered scratch, no trailing barrier.
  // Reduce+store by tid in [96,192): wave 0 issues NO slow sc1 store here.
  auto produce_gi = [&](int s) {
    int par = s & 1;
    int cbase = 16 * (l & 15);
    float xr[16];
#pragma unroll
    for (int k = 0; k < 16; k++) xr[k] = X[(size_t)s * NDIM + cbase + k];
    float p[6];
#pragma unroll
    for (int i = 0; i < 6; i++) {
      float a = 0.f;
#pragma unroll
      for (int k = 0; k < 16; k++) a = fmaf(wih[i][k], xr[k], a);
      p[i] = a;
    }
    int rl = w * 24 + (l >> 4) * 6;
    int lc = l & 15;
#pragma unroll
    for (int i = 0; i < 6; i++) red2[par][(rl + i) * 20 + lc] = p[i];
    __syncthreads();
    if (tid >= 96 && tid < 192) {
      int r = tid - 96;
      float a = 0.f;
#pragma unroll
      for (int k = 0; k < 16; k += 4) {
        float4 v = *(const float4*)&red2[par][r * 20 + k];
        a += v.x + v.y + v.z + v.w;
      }
      a += b_ih[96 * b + r];
      st_cohf(&RING[(size_t)(s & 3) * 1536 + 96 * b + r], a);
    }
  };

  auto compute_gh = [&](float* dst) {
    int cb = 16 * (l & 31);
    float hr[16];
#pragma unroll
    for (int k = 0; k < 16; k += 4) *(float4*)&hr[k] = *(const float4*)&hnew[cb + k];
    int rb = 96 * b + w * 24 + (l >> 5) * 12;
    float p[12];
#pragma unroll
    for (int i = 0; i < 12; i++) {
      float a = 0.f;
      const float* wr = &W_hh[(size_t)(rb + i) * MDIM + cb];
#pragma unroll
      for (int k = 0; k < 16; k++) a = fmaf(wr[k], hr[k], a);
      p[i] = a;
    }
    int rl = w * 24 + (l >> 5) * 12;
    int lc = l & 31;
#pragma unroll
    for (int i = 0; i < 12; i++) red[(rl + i) * 36 + lc] = p[i];
    __syncthreads();
    if (tid >= 96 && tid < 192) {
      int r = tid - 96;
      float a = 0.f;
#pragma unroll
      for (int k = 0; k < 32; k += 4) {
        float4 v = *(const float4*)&red[r * 36 + k];
        a += v.x + v.y + v.z + v.w;
      }
      a += b_hh[96 * b + r];
      st_cohf(&dst[96 * b + r], a);
    }
    __syncthreads();
  };

  // ---- startup: gi(0..2), gh(h0) ----
  produce_gi(0);
  produce_gi(1);
  produce_gi(2);
  __syncthreads();
  compute_gh(GHS);
  if (tid == 0) st_flag_rel(&F[b], 1ull);
  if (w == 0) {
    int guard = 0;
    bool done = false;
    while (!done) {
      u64 v = (l < G) ? ld_flag(&F[l]) : 1ull;
      done = (__ballot((int)(v == 1ull)) == ~0ull);
      if (++guard > (1 << 22)) break;
    }
  }
  __syncthreads();

  const float* ghsrc = GHS;
  bool prevReadHit = false;
  int  qprev = 0;

  for (int t = 0; t < T_STEPS; ++t) {
    // ---- issue all dependent sc1 loads up front ----
    float g0 = ld_cohf(&ghsrc[tid]);
    float g1 = ld_cohf(&ghsrc[tid + 256]);
    float g2 = ld_cohf(&ghsrc[512 + tid]);
    float g3 = ld_cohf(&ghsrc[512 + tid + 256]);
    float g4 = ld_cohf(&ghsrc[1024 + tid]);
    float g5 = ld_cohf(&ghsrc[1024 + tid + 256]);
    float m0 = 0.f, m1 = 0.f;
    if (prevReadHit) {
      m0 = ld_cohf(&Mrow[(size_t)qprev * 512 + tid]);
      m1 = ld_cohf(&Mrow[(size_t)qprev * 512 + tid + 256]);
    }
    const float* gi = &RING[(size_t)(t & 3) * 1536];
    float i0 = ld_cohf(&gi[tid]);
    float i1 = ld_cohf(&gi[tid + 256]);
    float i2 = ld_cohf(&gi[512 + tid]);
    float i3 = ld_cohf(&gi[512 + tid + 256]);
    float i4 = ld_cohf(&gi[1024 + tid]);
    float i5 = ld_cohf(&gi[1024 + tid + 256]);

    // lagged H write for read-hit step t-1 (plain store: fast L2 ack)
    if (prevReadHit) {
      H[(size_t)(t - 1) * 512 + tid]       = m0;
      H[(size_t)(t - 1) * 512 + tid + 256] = m1;
    }

    // ---- overlap gi production with the gh/gi MALL load latency ----
    // Safe: step-(t-1) poll confirmed all blocks consumed gi(t-1), whose
    // RING slot (t+3)&3 we overwrite here.
    if (t + 3 < T_STEPS) produce_gi(t + 3);

    // ---- gates (torch GRU semantics) ----
    float hp0 = prevReadHit ? m0 : hnew[tid];
    float hp1 = prevReadHit ? m1 : hnew[tid + 256];
    float r0 = sigm(i0 + g0), r1 = sigm(i1 + g1);
    float z0 = sigm(i2 + g2), z1 = sigm(i3 + g3);
    float n0 = tanh_(fmaf(r0, g4, i4)), n1 = tanh_(fmaf(r1, g5, i5));
    float hn0 = fmaf(z0, hp0 - n0, n0);
    float hn1 = fmaf(z1, hp1 - n1, n1);
    hnew[tid]       = hn0;
    hnew[tid + 256] = hn1;
    __syncthreads();                               // B1

    // ---- logits slice (32 rows) from register-resident C_w ----
    {
      int cb = 16 * (l & 31);
      float hr[16];
#pragma unroll
      for (int k = 0; k < 16; k += 4) *(float4*)&hr[k] = *(const float4*)&hnew[cb + k];
      float p0 = 0.f, p1 = 0.f, p2 = 0.f, p3 = 0.f;
#pragma unroll
      for (int k = 0; k < 16; k++) {
        p0 = fmaf(cw[0][k], hr[k], p0);
        p1 = fmaf(cw[1][k], hr[k], p1);
        p2 = fmaf(cw[2][k], hr[k], p2);
        p3 = fmaf(cw[3][k], hr[k], p3);
      }
      int rl = w * 8 + (l >> 5) * 4;
      int lc = l & 31;
      red[(rl + 0) * 36 + lc] = p0;
      red[(rl + 1) * 36 + lc] = p1;
      red[(rl + 2) * 36 + lc] = p2;
      red[(rl + 3) * 36 + lc] = p3;
    }
    __syncthreads();                               // B2

    // ---- key reduce + flagB store on WAVE 1 (lanes 0-31): wave 0 polls clean ----
    if (tid >= 64 && tid < 96) {
      int r = tid - 64;
      double a = 0.0;   // double final reduce: argmax robustness
#pragma unroll
      for (int k = 0; k < 32; k += 4) {
        float4 v = *(const float4*)&red[r * 36 + k];
        a += (double)v.x + (double)v.y + (double)v.z + (double)v.w;
      }
      a += (double)C_b[32 * b + r];
      float af = (float)a;
      u32 bits = __float_as_uint(af);
      u32 ord  = (bits & 0x80000000u) ? ~bits : (bits | 0x80000000u);
      int gidx = 32 * b + r;
      u64 key = ((u64)ord << 9) | (u64)(511 - gidx);
#pragma unroll
      for (int off = 16; off >= 1; off >>= 1) {
        u64 other = __shfl_xor(key, off, 64);
        if (other > key) key = other;
      }
      // self-contained epoch+key word: RELAXED store, no drain
      if (tid == 64)
        st_flag_rlx(&F[16 + (size_t)(t & 1) * 16 + b], ((u64)(t + 1) << 41) | key);
    }

    // ---- poll all blocks' keys, pick global argmax (wave 0, empty vmem queue) ----
    if (w == 0) {
      u64 v = 0;
      int guard = 0;
      for (;;) {
        v = (l < G) ? ld_flag(&F[16 + (size_t)(t & 1) * 16 + l]) : 0;
        bool ok = (l >= G) || ((v >> 41) == (u64)(t + 1));
        if (__ballot((int)ok) == ~0ull) break;
        if (++guard > (1 << 22)) break;
      }
      u64 key = (l < G) ? (v & ((1ull << 41) - 1)) : 0;
#pragma unroll
      for (int off = 8; off >= 1; off >>= 1) {
        u64 other = __shfl_xor(key, off, 64);
        if (other > key) key = other;
      }
      if (l == 0) {
        int q = 511 - (int)(key & 0x1FFu);
        u32 wr = written[q];
        u32 fresh = (q > 0 && wr == 0u) ? 1u : 0u;
        u32 rhit  = (q > 0 && wr != 0u) ? 1u : 0u;
        if (fresh) written[q] = 1u;
        bc[0] = (u32)q | (fresh << 16) | (rhit << 17);
      }
    }
    __syncthreads();                               // B4
    u32 info = bc[0];
    int  q     = (int)(info & 0xFFFFu);
    bool fresh = (info >> 16) & 1u;
    bool rhit  = (info >> 17) & 1u;

    if (!rhit) {
      // h_out = h_new: emit H[t]; compute gh for next step (rare path)
      H[(size_t)t * 512 + tid]       = hnew[tid];
      H[(size_t)t * 512 + tid + 256] = hnew[tid + 256];
      float* dst;
      if (fresh) {
        if (tid >= 64 && tid < 96) {
          int r = tid - 64;
          st_cohf(&Mrow[(size_t)q * 512 + 32 * b + r], hnew[32 * b + r]);
        }
        dst = &GH[(size_t)q * 1536];
      } else {
        dst = GHS;
      }
      compute_gh(dst);
      // compute_gh's trailing barrier drained all sc1 stores -> release flag sound
      if (tid == 0) st_flag_rel(&F[48 + (size_t)(t & 1) * 16 + b], (u64)(t + 1));
      if (w == 0) {
        int guard = 0;
        for (;;) {
          u64 v = (l < G) ? ld_flag(&F[48 + (size_t)(t & 1) * 16 + l]) : 0;
          bool ok = (l >= G) || (v == (u64)(t + 1));
          if (__ballot((int)ok) == ~0ull) break;
          if (++guard > (1 << 22)) break;
        }
      }
      __syncthreads();
      ghsrc = dst;
      prevReadHit = false;
    } else {
      ghsrc = &GH[(size_t)q * 1536];
      prevReadHit = true;
      qprev = q;
    }
  }

  // epilogue: H[T-1] for trailing read-hit
  if (prevReadHit) {
    float a = ld_cohf(&Mrow[(size_t)qprev * 512 + tid]);
    float c = ld_cohf(&Mrow[(size_t)qprev * 512 + tid + 256]);
    H[(size_t)(T_STEPS - 1) * 512 + tid]       = a;
    H[(size_t)(T_STEPS - 1) * 512 + tid + 256] = c;
  }
}

// ---- V_w transpose ----
__global__ void vw_transpose(const float* __restrict__ Vw, float* __restrict__ VwT) {
  int idx = blockIdx.x * 256 + threadIdx.x;
  int kk = idx >> 8, ll = idx & 255;
  VwT[idx] = Vw[(size_t)ll * MDIM + kk];
}

// ---- Y = H @ V_w^T + V_b ----
__global__ __launch_bounds__(256) void y_gemm(const float* __restrict__ Hm,
                                              const float* __restrict__ VwT,
                                              const float* __restrict__ Vb,
                                              float* __restrict__ Y) {
  int t0 = blockIdx.x * 16;
  int tid = threadIdx.x;
  __shared__ __align__(16) float hs[16 * MDIM];
  for (int i = tid; i < 16 * MDIM; i += 256)
    hs[i] = Hm[(size_t)t0 * MDIM + i];
  __syncthreads();
  float acc[16];
  float vb = Vb[tid];
#pragma unroll
  for (int r = 0; r < 16; r++) acc[r] = vb;
  for (int k = 0; k < MDIM; k += 4) {
    float v0 = VwT[(size_t)(k + 0) * LOUT + tid];
    float v1 = VwT[(size_t)(k + 1) * LOUT + tid];
    float v2 = VwT[(size_t)(k + 2) * LOUT + tid];
    float v3 = VwT[(size_t)(k + 3) * LOUT + tid];
#pragma unroll
    for (int r = 0; r < 16; r++) {
      float4 h4 = *(const float4*)&hs[r * MDIM + k];
      acc[r] = fmaf(h4.x, v0, fmaf(h4.y, v1, fmaf(h4.z, v2, fmaf(h4.w, v3, acc[r]))));
    }
  }
#pragma unroll
  for (int r = 0; r < 16; r++)
    Y[(size_t)(t0 + r) * LOUT + tid] = acc[r];
}

extern "C" void kernel_launch(void* const* d_in, const int* in_sizes, int n_in,
                              void* d_out, int out_size, void* d_ws, size_t ws_size,
                              hipStream_t stream) {
  const float* X    = (const float*)d_in[0];
  const float* h0   = (const float*)d_in[1];
  const float* W_ih = (const float*)d_in[2];
  const float* W_hh = (const float*)d_in[3];
  const float* b_ih = (const float*)d_in[4];
  const float* b_hh = (const float*)d_in[5];
  const float* C_w  = (const float*)d_in[6];
  const float* C_b  = (const float*)d_in[7];
  const float* V_w  = (const float*)d_in[8];
  const float* V_b  = (const float*)d_in[9];
  float* ws  = (float*)d_ws;
  float* VwT = ws + OFF_VWT;
  float* Hm  = ws + OFF_H;

  hipLaunchKernelGGL(vw_transpose, dim3(512), dim3(256), 0, stream, V_w, VwT);
  hipLaunchKernelGGL(dmm_main, dim3(G), dim3(TPB), 0, stream,
                     X, h0, W_ih, W_hh, b_ih, b_hh, C_w, C_b, ws);
  hipLaunchKernelGGL(y_gemm, dim3(T_STEPS / 16), dim3(256), 0, stream,
                     Hm, VwT, V_b, (float*)d_out);
}

// Round 7
// 50376.825 us; speedup vs baseline: 1.4283x; 1.4283x over previous
//
#include <hip/hip_runtime.h>
#include <stdint.h>

#define T_STEPS 16384
#define NDIM 256
#define MDIM 512
#define KP1 512
#define LOUT 256
#define G 16
#define TPB 256

typedef unsigned long long u64;
typedef unsigned int u32;

// ---- ws layout (float offsets) ----
constexpr size_t OFF_GH    = 0;                         // [512][1536] cached W_hh@M[q]+b_hh
constexpr size_t OFF_GHS   = 512ull * 1536;             // [1536] scratch gh (q==0 / startup)
constexpr size_t OFF_M     = OFF_GHS + 1536;            // [512][512] memory rows
constexpr size_t OFF_RING  = OFF_M + 512ull * 512;      // [4][1536] gi ring
constexpr size_t OFF_H     = OFF_RING + 4ull * 1536;    // [16384][512] hidden outputs
constexpr size_t OFF_VWT   = OFF_H + 16384ull * 512;    // [512][256] V_w transposed
constexpr size_t OFF_FLAGS = OFF_VWT + 512ull * 256;    // u64 flags (compact layout)

__device__ __forceinline__ float ld_cohf(const float* p) {
  return __hip_atomic_load(p, __ATOMIC_RELAXED, __HIP_MEMORY_SCOPE_AGENT);
}
__device__ __forceinline__ void st_cohf(float* p, float v) {
  __hip_atomic_store(p, v, __ATOMIC_RELAXED, __HIP_MEMORY_SCOPE_AGENT);
}
__device__ __forceinline__ u64 ld_flag(const u64* p) {
  return __hip_atomic_load(p, __ATOMIC_RELAXED, __HIP_MEMORY_SCOPE_AGENT);
}
__device__ __forceinline__ void st_flag_rel(u64* p, u64 v) {
  __hip_atomic_store(p, v, __ATOMIC_RELEASE, __HIP_MEMORY_SCOPE_AGENT);
}
__device__ __forceinline__ void st_flag_rlx(u64* p, u64 v) {
  __hip_atomic_store(p, v, __ATOMIC_RELAXED, __HIP_MEMORY_SCOPE_AGENT);
}

__device__ __forceinline__ float sigm(float x) {
  return __builtin_amdgcn_rcpf(1.0f + __expf(-x));
}
__device__ __forceinline__ float tanh_(float x) {
  return 1.0f - 2.0f * __builtin_amdgcn_rcpf(__expf(2.0f * x) + 1.0f);
}

__global__ __launch_bounds__(TPB, 1) void dmm_main(
    const float* __restrict__ X, const float* __restrict__ h0,
    const float* __restrict__ W_ih, const float* __restrict__ W_hh,
    const float* __restrict__ b_ih, const float* __restrict__ b_hh,
    const float* __restrict__ C_w, const float* __restrict__ C_b,
    float* __restrict__ ws)
{
  const int b   = blockIdx.x;
  const int tid = threadIdx.x;
  const int w   = tid >> 6;
  const int l   = tid & 63;

  float* GH   = ws + OFF_GH;
  float* GHS  = ws + OFF_GHS;
  float* Mrow = ws + OFF_M;
  float* RING = ws + OFF_RING;
  float* H    = ws + OFF_H;
  u64*   F    = (u64*)(ws + OFF_FLAGS);
  // flagS = F[0..15], flagB = F[16 + p*16 + b], flagC = F[48 + p*16 + b]

  __shared__ __align__(16) float hnew[MDIM];
  __shared__ __align__(16) float red[96 * 36];   // logits reduce + gh reduce (rare path)
  __shared__ u32 written[KP1];
  __shared__ u32 bc[4];

  // ---- persistent register-resident weight slices ----
  // produce (waves 1..3): 32 rows/wave, 8 rows/lane-group-member, 16-col slice
  const int pw   = (w >= 1) ? (w - 1) : 0;
  const int rloc = pw * 32 + (l >> 4) * 8;        // local row base 0..95 (waves 1-3)
  float wih[8][16];
  {
    int rbase = 96 * b + rloc;
    int cbase = 16 * (l & 15);
#pragma unroll
    for (int i = 0; i < 8; i++)
#pragma unroll
      for (int k = 0; k < 16; k++)
        wih[i][k] = W_ih[(size_t)(rbase + i) * NDIM + cbase + k];
  }
  float bihr[8];
#pragma unroll
  for (int i = 0; i < 8; i++) bihr[i] = b_ih[96 * b + rloc + i];

  // logits: rows rl = w*8 + (l>>5)*4 + i (32/block), cols 16*(l&31)+k
  float cw[4][16];
  {
    int rbase = 32 * b + w * 8 + (l >> 5) * 4;
    int cbase = 16 * (l & 31);
#pragma unroll
    for (int i = 0; i < 4; i++)
#pragma unroll
      for (int k = 0; k < 16; k++)
        cw[i][k] = C_w[(size_t)(rbase + i) * MDIM + cbase + k];
  }

  for (int i = tid; i < KP1; i += TPB) written[i] = 0u;
  hnew[tid]       = h0[tid];
  hnew[tid + 256] = h0[tid + 256];
  __syncthreads();

  // ---- produce gi(s): shfl-only, barrier-free; CALL ONLY ON WAVES 1..3 ----
  auto produce_gi = [&](int s) {
    int cbase = 16 * (l & 15);
    float xr[16];
#pragma unroll
    for (int k = 0; k < 16; k++) xr[k] = X[(size_t)s * NDIM + cbase + k];
    float p[8];
#pragma unroll
    for (int i = 0; i < 8; i++) {
      float a = 0.f;
#pragma unroll
      for (int k = 0; k < 16; k++) a = fmaf(wih[i][k], xr[k], a);
      p[i] = a;
    }
    // butterfly over the 16-lane group (offsets 1,2,4,8 keep within group)
#pragma unroll
    for (int off = 1; off <= 8; off <<= 1) {
#pragma unroll
      for (int i = 0; i < 8; i++) p[i] += __shfl_xor(p[i], off, 64);
    }
    if ((l & 15) == 0) {
      float* dst = &RING[(size_t)(s & 3) * 1536 + 96 * b + rloc];
#pragma unroll
      for (int i = 0; i < 8; i++) st_cohf(&dst[i], p[i] + bihr[i]);
    }
  };

  auto compute_gh = [&](float* dst) {
    int cb = 16 * (l & 31);
    float hr[16];
#pragma unroll
    for (int k = 0; k < 16; k += 4) *(float4*)&hr[k] = *(const float4*)&hnew[cb + k];
    int rb = 96 * b + w * 24 + (l >> 5) * 12;
    float p[12];
#pragma unroll
    for (int i = 0; i < 12; i++) {
      float a = 0.f;
      const float* wr = &W_hh[(size_t)(rb + i) * MDIM + cb];
#pragma unroll
      for (int k = 0; k < 16; k++) a = fmaf(wr[k], hr[k], a);
      p[i] = a;
    }
    int rl = w * 24 + (l >> 5) * 12;
    int lc = l & 31;
#pragma unroll
    for (int i = 0; i < 12; i++) red[(rl + i) * 36 + lc] = p[i];
    __syncthreads();
    if (tid < 96) {
      float a = 0.f;
#pragma unroll
      for (int k = 0; k < 32; k += 4) {
        float4 v = *(const float4*)&red[tid * 36 + k];
        a += v.x + v.y + v.z + v.w;
      }
      a += b_hh[96 * b + tid];
      st_cohf(&dst[96 * b + tid], a);
    }
    __syncthreads();
  };

  // ---- startup: gi(0..2) by waves 1-3, gh(h0) ----
  if (w >= 1) {
    produce_gi(0);
    produce_gi(1);
    produce_gi(2);
  }
  __syncthreads();
  compute_gh(GHS);
  if (tid == 0) st_flag_rel(&F[b], 1ull);
  if (w == 0) {
    int guard = 0;
    bool done = false;
    while (!done) {
      u64 v = (l < G) ? ld_flag(&F[l]) : 1ull;
      done = (__ballot((int)(v == 1ull)) == ~0ull);
      if (++guard > (1 << 22)) break;
    }
  }
  __syncthreads();

  const float* ghsrc = GHS;
  bool prevReadHit = false;
  int  qprev = 0;

  for (int t = 0; t < T_STEPS; ++t) {
    // ---- issue all dependent sc1 loads up front ----
    float g0 = ld_cohf(&ghsrc[tid]);
    float g1 = ld_cohf(&ghsrc[tid + 256]);
    float g2 = ld_cohf(&ghsrc[512 + tid]);
    float g3 = ld_cohf(&ghsrc[512 + tid + 256]);
    float g4 = ld_cohf(&ghsrc[1024 + tid]);
    float g5 = ld_cohf(&ghsrc[1024 + tid + 256]);
    float m0 = 0.f, m1 = 0.f;
    if (prevReadHit) {
      m0 = ld_cohf(&Mrow[(size_t)qprev * 512 + tid]);
      m1 = ld_cohf(&Mrow[(size_t)qprev * 512 + tid + 256]);
    }
    const float* gi = &RING[(size_t)(t & 3) * 1536];
    float i0 = ld_cohf(&gi[tid]);
    float i1 = ld_cohf(&gi[tid + 256]);
    float i2 = ld_cohf(&gi[512 + tid]);
    float i3 = ld_cohf(&gi[512 + tid + 256]);
    float i4 = ld_cohf(&gi[1024 + tid]);
    float i5 = ld_cohf(&gi[1024 + tid + 256]);

    // lagged H write for read-hit step t-1 (plain store: fast L2 ack)
    if (prevReadHit) {
      H[(size_t)(t - 1) * 512 + tid]       = m0;
      H[(size_t)(t - 1) * 512 + tid + 256] = m1;
    }

    // ---- gates (torch GRU semantics) ----
    float hp0 = prevReadHit ? m0 : hnew[tid];
    float hp1 = prevReadHit ? m1 : hnew[tid + 256];
    float r0 = sigm(i0 + g0), r1 = sigm(i1 + g1);
    float z0 = sigm(i2 + g2), z1 = sigm(i3 + g3);
    float n0 = tanh_(fmaf(r0, g4, i4)), n1 = tanh_(fmaf(r1, g5, i5));
    float hn0 = fmaf(z0, hp0 - n0, n0);
    float hn1 = fmaf(z1, hp1 - n1, n1);
    hnew[tid]       = hn0;
    hnew[tid + 256] = hn1;
    __syncthreads();                               // B1

    // ---- logits slice (32 rows) from register-resident C_w ----
    {
      int cb = 16 * (l & 31);
      float hr[16];
#pragma unroll
      for (int k = 0; k < 16; k += 4) *(float4*)&hr[k] = *(const float4*)&hnew[cb + k];
      float p0 = 0.f, p1 = 0.f, p2 = 0.f, p3 = 0.f;
#pragma unroll
      for (int k = 0; k < 16; k++) {
        p0 = fmaf(cw[0][k], hr[k], p0);
        p1 = fmaf(cw[1][k], hr[k], p1);
        p2 = fmaf(cw[2][k], hr[k], p2);
        p3 = fmaf(cw[3][k], hr[k], p3);
      }
      int rl = w * 8 + (l >> 5) * 4;
      int lc = l & 31;
      red[(rl + 0) * 36 + lc] = p0;
      red[(rl + 1) * 36 + lc] = p1;
      red[(rl + 2) * 36 + lc] = p2;
      red[(rl + 3) * 36 + lc] = p3;
    }
    __syncthreads();                               // B2

    // ---- key reduce: redundantly on waves 0 AND 1 (wave 1 stores flagB,
    //      wave 0 keeps the key in-register and polls store-free) ----
    u64 ownkey = 0;
    if (w <= 1) {
      u64 key = 0;
      if (l < 32) {
        double a = 0.0;   // double final reduce: argmax robustness
#pragma unroll
        for (int k = 0; k < 32; k += 4) {
          float4 v = *(const float4*)&red[l * 36 + k];
          a += (double)v.x + (double)v.y + (double)v.z + (double)v.w;
        }
        a += (double)C_b[32 * b + l];
        float af = (float)a;
        u32 bits = __float_as_uint(af);
        u32 ord  = (bits & 0x80000000u) ? ~bits : (bits | 0x80000000u);
        int gidx = 32 * b + l;
        key = ((u64)ord << 9) | (u64)(511 - gidx);
      }
#pragma unroll
      for (int off = 32; off >= 1; off >>= 1) {
        u64 other = __shfl_xor(key, off, 64);
        if (other > key) key = other;
      }
      if (tid == 64)   // wave 1 lane 0: the only hot-path flagB store
        st_flag_rlx(&F[16 + (size_t)(t & 1) * 16 + b], ((u64)(t + 1) << 41) | key);
      ownkey = key;
    }

    // ---- produce gi(t+3) on waves 1-3 (barrier-free) while wave 0 polls ----
    if (w >= 1 && t + 3 < T_STEPS) produce_gi(t + 3);

    // ---- poll 15 remote keys (own key in-register), pick global argmax ----
    if (w == 0) {
      u64 v = 0;
      int guard = 0;
      const bool need = (l < G) && (l != b);
      for (;;) {
        v = need ? ld_flag(&F[16 + (size_t)(t & 1) * 16 + l]) : 0;
        bool ok = !need || ((v >> 41) == (u64)(t + 1));
        if (__ballot((int)ok) == ~0ull) break;
        if (++guard > (1 << 22)) break;
      }
      u64 key = (l < G) ? ((l == b) ? ownkey : (v & ((1ull << 41) - 1))) : 0;
#pragma unroll
      for (int off = 8; off >= 1; off >>= 1) {
        u64 other = __shfl_xor(key, off, 64);
        if (other > key) key = other;
      }
      if (l == 0) {
        int q = 511 - (int)(key & 0x1FFu);
        u32 wr = written[q];
        u32 fresh = (q > 0 && wr == 0u) ? 1u : 0u;
        u32 rhit  = (q > 0 && wr != 0u) ? 1u : 0u;
        if (fresh) written[q] = 1u;
        bc[0] = (u32)q | (fresh << 16) | (rhit << 17);
      }
    }
    __syncthreads();                               // B4
    u32 info = bc[0];
    int  q     = (int)(info & 0xFFFFu);
    bool fresh = (info >> 16) & 1u;
    bool rhit  = (info >> 17) & 1u;

    if (!rhit) {
      // h_out = h_new: emit H[t]; compute gh for next step (rare path)
      H[(size_t)t * 512 + tid]       = hnew[tid];
      H[(size_t)t * 512 + tid + 256] = hnew[tid + 256];
      float* dst;
      if (fresh) {
        if (tid < 32) st_cohf(&Mrow[(size_t)q * 512 + 32 * b + tid], hnew[32 * b + tid]);
        dst = &GH[(size_t)q * 1536];
      } else {
        dst = GHS;
      }
      compute_gh(dst);
      if (tid == 0) st_flag_rel(&F[48 + (size_t)(t & 1) * 16 + b], (u64)(t + 1));
      if (w == 0) {
        int guard = 0;
        for (;;) {
          u64 v = (l < G) ? ld_flag(&F[48 + (size_t)(t & 1) * 16 + l]) : 0;
          bool ok = (l >= G) || (v == (u64)(t + 1));
          if (__ballot((int)ok) == ~0ull) break;
          if (++guard > (1 << 22)) break;
        }
      }
      __syncthreads();
      ghsrc = dst;
      prevReadHit = false;
    } else {
      ghsrc = &GH[(size_t)q * 1536];
      prevReadHit = true;
      qprev = q;
    }
  }

  // epilogue: H[T-1] for trailing read-hit
  if (prevReadHit) {
    float a = ld_cohf(&Mrow[(size_t)qprev * 512 + tid]);
    float c = ld_cohf(&Mrow[(size_t)qprev * 512 + tid + 256]);
    H[(size_t)(T_STEPS - 1) * 512 + tid]       = a;
    H[(size_t)(T_STEPS - 1) * 512 + tid + 256] = c;
  }
}

// ---- V_w transpose ----
__global__ void vw_transpose(const float* __restrict__ Vw, float* __restrict__ VwT) {
  int idx = blockIdx.x * 256 + threadIdx.x;
  int kk = idx >> 8, ll = idx & 255;
  VwT[idx] = Vw[(size_t)ll * MDIM + kk];
}

// ---- Y = H @ V_w^T + V_b ----
__global__ __launch_bounds__(256) void y_gemm(const float* __restrict__ Hm,
                                              const float* __restrict__ VwT,
                                              const float* __restrict__ Vb,
                                              float* __restrict__ Y) {
  int t0 = blockIdx.x * 16;
  int tid = threadIdx.x;
  __shared__ __align__(16) float hs[16 * MDIM];
  for (int i = tid; i < 16 * MDIM; i += 256)
    hs[i] = Hm[(size_t)t0 * MDIM + i];
  __syncthreads();
  float acc[16];
  float vb = Vb[tid];
#pragma unroll
  for (int r = 0; r < 16; r++) acc[r] = vb;
  for (int k = 0; k < MDIM; k += 4) {
    float v0 = VwT[(size_t)(k + 0) * LOUT + tid];
    float v1 = VwT[(size_t)(k + 1) * LOUT + tid];
    float v2 = VwT[(size_t)(k + 2) * LOUT + tid];
    float v3 = VwT[(size_t)(k + 3) * LOUT + tid];
#pragma unroll
    for (int r = 0; r < 16; r++) {
      float4 h4 = *(const float4*)&hs[r * MDIM + k];
      acc[r] = fmaf(h4.x, v0, fmaf(h4.y, v1, fmaf(h4.z, v2, fmaf(h4.w, v3, acc[r]))));
    }
  }
#pragma unroll
  for (int r = 0; r < 16; r++)
    Y[(size_t)(t0 + r) * LOUT + tid] = acc[r];
}

extern "C" void kernel_launch(void* const* d_in, const int* in_sizes, int n_in,
                              void* d_out, int out_size, void* d_ws, size_t ws_size,
                              hipStream_t stream) {
  const float* X    = (const float*)d_in[0];
  const float* h0   = (const float*)d_in[1];
  const float* W_ih = (const float*)d_in[2];
  const float* W_hh = (const float*)d_in[3];
  const float* b_ih = (const float*)d_in[4];
  const float* b_hh = (const float*)d_in[5];
  const float* C_w  = (const float*)d_in[6];
  const float* C_b  = (const float*)d_in[7];
  const float* V_w  = (const float*)d_in[8];
  const float* V_b  = (const float*)d_in[9];
  float* ws  = (float*)d_ws;
  float* VwT = ws + OFF_VWT;
  float* Hm  = ws + OFF_H;

  hipLaunchKernelGGL(vw_transpose, dim3(512), dim3(256), 0, stream, V_w, VwT);
  hipLaunchKernelGGL(dmm_main, dim3(G), dim3(TPB), 0, stream,
                     X, h0, W_ih, W_hh, b_ih, b_hh, C_w, C_b, ws);
  hipLaunchKernelGGL(y_gemm, dim3(T_STEPS / 16), dim3(256), 0, stream,
                     Hm, VwT, V_b, (float*)d_out);
}

// Round 8
// 45010.590 us; speedup vs baseline: 1.5986x; 1.1192x over previous
//
#include <hip/hip_runtime.h>
#include <stdint.h>

#define T_STEPS 16384
#define NDIM 256
#define MDIM 512
#define KP1 512
#define LOUT 256
#define G 16
#define TPB 256

typedef unsigned long long u64;
typedef unsigned int u32;

// ---- ws layout (float offsets) ----
constexpr size_t OFF_GH    = 0;                         // [512][1536] cached W_hh@M[q]+b_hh
constexpr size_t OFF_GHS   = 512ull * 1536;             // [1536] scratch gh (q==0 / startup)
constexpr size_t OFF_M     = OFF_GHS + 1536;            // [512][512] memory rows
constexpr size_t OFF_RING  = OFF_M + 512ull * 512;      // [4][1536] gi ring
constexpr size_t OFF_H     = OFF_RING + 4ull * 1536;    // [16384][512] hidden outputs
constexpr size_t OFF_VWT   = OFF_H + 16384ull * 512;    // [512][256] V_w transposed
constexpr size_t OFF_FLAGS = OFF_VWT + 512ull * 256;    // u64 flags (compact layout)

__device__ __forceinline__ float ld_cohf(const float* p) {
  return __hip_atomic_load(p, __ATOMIC_RELAXED, __HIP_MEMORY_SCOPE_AGENT);
}
__device__ __forceinline__ void st_cohf(float* p, float v) {
  __hip_atomic_store(p, v, __ATOMIC_RELAXED, __HIP_MEMORY_SCOPE_AGENT);
}
__device__ __forceinline__ u64 ld_flag(const u64* p) {
  return __hip_atomic_load(p, __ATOMIC_RELAXED, __HIP_MEMORY_SCOPE_AGENT);
}
__device__ __forceinline__ void st_flag_rel(u64* p, u64 v) {
  __hip_atomic_store(p, v, __ATOMIC_RELEASE, __HIP_MEMORY_SCOPE_AGENT);
}
__device__ __forceinline__ void st_flag_rlx(u64* p, u64 v) {
  __hip_atomic_store(p, v, __ATOMIC_RELAXED, __HIP_MEMORY_SCOPE_AGENT);
}

__device__ __forceinline__ float sigm(float x) {
  return __builtin_amdgcn_rcpf(1.0f + __expf(-x));
}
__device__ __forceinline__ float tanh_(float x) {
  return 1.0f - 2.0f * __builtin_amdgcn_rcpf(__expf(2.0f * x) + 1.0f);
}

// ---- DPP max-reduce helpers (VALU-rate cross-lane, no ds_bpermute) ----
template<int CTRL>
__device__ __forceinline__ u32 dppmax(u32 v) {
  u32 t = (u32)__builtin_amdgcn_update_dpp(0, (int)v, CTRL, 0xf, 0xf, true);
  return v > t ? v : t;
}
// full-wave max; returns wave-uniform result (via lane 63)
__device__ __forceinline__ u32 wave_max_u32(u32 v) {
  v = dppmax<0x111>(v);   // row_shr:1
  v = dppmax<0x112>(v);   // row_shr:2
  v = dppmax<0x114>(v);   // row_shr:4
  v = dppmax<0x118>(v);   // row_shr:8
  v = dppmax<0x142>(v);   // row_bcast:15
  v = dppmax<0x143>(v);   // row_bcast:31
  return (u32)__builtin_amdgcn_readlane((int)v, 63);
}
// max over lanes 0-15 (others must carry 0); wave-uniform result via lane 15
__device__ __forceinline__ u32 row16_max_u32(u32 v) {
  v = dppmax<0x111>(v);
  v = dppmax<0x112>(v);
  v = dppmax<0x114>(v);
  v = dppmax<0x118>(v);
  return (u32)__builtin_amdgcn_readlane((int)v, 15);
}

__global__ __launch_bounds__(TPB, 1) void dmm_main(
    const float* __restrict__ X, const float* __restrict__ h0,
    const float* __restrict__ W_ih, const float* __restrict__ W_hh,
    const float* __restrict__ b_ih, const float* __restrict__ b_hh,
    const float* __restrict__ C_w, const float* __restrict__ C_b,
    float* __restrict__ ws)
{
  const int b   = blockIdx.x;
  const int tid = threadIdx.x;
  const int w   = tid >> 6;
  const int l   = tid & 63;

  float* GH   = ws + OFF_GH;
  float* GHS  = ws + OFF_GHS;
  float* Mrow = ws + OFF_M;
  float* RING = ws + OFF_RING;
  float* H    = ws + OFF_H;
  u64*   F    = (u64*)(ws + OFF_FLAGS);
  // flagS = F[0..15], flagB = F[16 + p*16 + b], flagC = F[48 + p*16 + b]

  __shared__ __align__(16) float hnew[MDIM];
  __shared__ __align__(16) float red[96 * 36];   // logits reduce + gh reduce (rare path)
  __shared__ u32 written[KP1];
  __shared__ u32 bcw;                            // (info<<4) | epoch4

  // ---- persistent register-resident weight slices ----
  const int pw   = (w >= 1) ? (w - 1) : 0;
  const int rloc = pw * 32 + (l >> 4) * 8;        // local row base 0..95 (waves 1-3)
  float wih[8][16];
  {
    int rbase = 96 * b + rloc;
    int cbase = 16 * (l & 15);
#pragma unroll
    for (int i = 0; i < 8; i++)
#pragma unroll
      for (int k = 0; k < 16; k++)
        wih[i][k] = W_ih[(size_t)(rbase + i) * NDIM + cbase + k];
  }
  float bihr[8];
#pragma unroll
  for (int i = 0; i < 8; i++) bihr[i] = b_ih[96 * b + rloc + i];

  float cw[4][16];
  {
    int rbase = 32 * b + w * 8 + (l >> 5) * 4;
    int cbase = 16 * (l & 31);
#pragma unroll
    for (int i = 0; i < 4; i++)
#pragma unroll
      for (int k = 0; k < 16; k++)
        cw[i][k] = C_w[(size_t)(rbase + i) * MDIM + cbase + k];
  }

  for (int i = tid; i < KP1; i += TPB) written[i] = 0u;
  if (tid == 0) bcw = 0u;
  hnew[tid]       = h0[tid];
  hnew[tid + 256] = h0[tid + 256];
  __syncthreads();

  // ---- produce gi(s): shfl-only, barrier-free; CALL ONLY ON WAVES 1..3 ----
  auto produce_gi = [&](int s) {
    int cbase = 16 * (l & 15);
    float xr[16];
#pragma unroll
    for (int k = 0; k < 16; k++) xr[k] = X[(size_t)s * NDIM + cbase + k];
    float p[8];
#pragma unroll
    for (int i = 0; i < 8; i++) {
      float a = 0.f;
#pragma unroll
      for (int k = 0; k < 16; k++) a = fmaf(wih[i][k], xr[k], a);
      p[i] = a;
    }
#pragma unroll
    for (int off = 1; off <= 8; off <<= 1) {
#pragma unroll
      for (int i = 0; i < 8; i++) p[i] += __shfl_xor(p[i], off, 64);
    }
    if ((l & 15) == 0) {
      float* dst = &RING[(size_t)(s & 3) * 1536 + 96 * b + rloc];
#pragma unroll
      for (int i = 0; i < 8; i++) st_cohf(&dst[i], p[i] + bihr[i]);
    }
  };

  auto compute_gh = [&](float* dst) {
    int cb = 16 * (l & 31);
    float hr[16];
#pragma unroll
    for (int k = 0; k < 16; k += 4) *(float4*)&hr[k] = *(const float4*)&hnew[cb + k];
    int rb = 96 * b + w * 24 + (l >> 5) * 12;
    float p[12];
#pragma unroll
    for (int i = 0; i < 12; i++) {
      float a = 0.f;
      const float* wr = &W_hh[(size_t)(rb + i) * MDIM + cb];
#pragma unroll
      for (int k = 0; k < 16; k++) a = fmaf(wr[k], hr[k], a);
      p[i] = a;
    }
    int rl = w * 24 + (l >> 5) * 12;
    int lc = l & 31;
#pragma unroll
    for (int i = 0; i < 12; i++) red[(rl + i) * 36 + lc] = p[i];
    __syncthreads();
    if (tid < 96) {
      float a = 0.f;
#pragma unroll
      for (int k = 0; k < 32; k += 4) {
        float4 v = *(const float4*)&red[tid * 36 + k];
        a += v.x + v.y + v.z + v.w;
      }
      a += b_hh[96 * b + tid];
      st_cohf(&dst[96 * b + tid], a);
    }
    __syncthreads();
  };

  // ---- startup: gi(0..2) by waves 1-3, gh(h0) ----
  if (w >= 1) {
    produce_gi(0);
    produce_gi(1);
    produce_gi(2);
  }
  __syncthreads();
  compute_gh(GHS);
  if (tid == 0) st_flag_rel(&F[b], 1ull);
  if (w == 0) {
    int guard = 0;
    bool done = false;
    while (!done) {
      u64 v = (l < G) ? ld_flag(&F[l]) : 1ull;
      done = (__ballot((int)(v == 1ull)) == ~0ull);
      if (++guard > (1 << 22)) break;
    }
  }
  __syncthreads();

  const float* ghsrc = GHS;
  bool prevReadHit = false;
  int  qprev = 0;

  for (int t = 0; t < T_STEPS; ++t) {
    // ---- issue all dependent sc1 loads up front ----
    float g0 = ld_cohf(&ghsrc[tid]);
    float g1 = ld_cohf(&ghsrc[tid + 256]);
    float g2 = ld_cohf(&ghsrc[512 + tid]);
    float g3 = ld_cohf(&ghsrc[512 + tid + 256]);
    float g4 = ld_cohf(&ghsrc[1024 + tid]);
    float g5 = ld_cohf(&ghsrc[1024 + tid + 256]);
    float m0 = 0.f, m1 = 0.f;
    if (prevReadHit) {
      m0 = ld_cohf(&Mrow[(size_t)qprev * 512 + tid]);
      m1 = ld_cohf(&Mrow[(size_t)qprev * 512 + tid + 256]);
    }
    const float* gi = &RING[(size_t)(t & 3) * 1536];
    float i0 = ld_cohf(&gi[tid]);
    float i1 = ld_cohf(&gi[tid + 256]);
    float i2 = ld_cohf(&gi[512 + tid]);
    float i3 = ld_cohf(&gi[512 + tid + 256]);
    float i4 = ld_cohf(&gi[1024 + tid]);
    float i5 = ld_cohf(&gi[1024 + tid + 256]);

    // lagged H write for read-hit step t-1 (plain store: fast L2 ack)
    if (prevReadHit) {
      H[(size_t)(t - 1) * 512 + tid]       = m0;
      H[(size_t)(t - 1) * 512 + tid + 256] = m1;
    }

    // ---- gates (torch GRU semantics) ----
    float hp0 = prevReadHit ? m0 : hnew[tid];
    float hp1 = prevReadHit ? m1 : hnew[tid + 256];
    float r0 = sigm(i0 + g0), r1 = sigm(i1 + g1);
    float z0 = sigm(i2 + g2), z1 = sigm(i3 + g3);
    float n0 = tanh_(fmaf(r0, g4, i4)), n1 = tanh_(fmaf(r1, g5, i5));
    float hn0 = fmaf(z0, hp0 - n0, n0);
    float hn1 = fmaf(z1, hp1 - n1, n1);
    hnew[tid]       = hn0;
    hnew[tid + 256] = hn1;
    __syncthreads();                               // B1

    // ---- logits slice (32 rows) from register-resident C_w ----
    {
      int cb = 16 * (l & 31);
      float hr[16];
#pragma unroll
      for (int k = 0; k < 16; k += 4) *(float4*)&hr[k] = *(const float4*)&hnew[cb + k];
      float p0 = 0.f, p1 = 0.f, p2 = 0.f, p3 = 0.f;
#pragma unroll
      for (int k = 0; k < 16; k++) {
        p0 = fmaf(cw[0][k], hr[k], p0);
        p1 = fmaf(cw[1][k], hr[k], p1);
        p2 = fmaf(cw[2][k], hr[k], p2);
        p3 = fmaf(cw[3][k], hr[k], p3);
      }
      int rl = w * 8 + (l >> 5) * 4;
      int lc = l & 31;
      red[(rl + 0) * 36 + lc] = p0;
      red[(rl + 1) * 36 + lc] = p1;
      red[(rl + 2) * 36 + lc] = p2;
      red[(rl + 3) * 36 + lc] = p3;
    }
    __syncthreads();                               // B2

    // ---- block key: DPP max over ord + ballot idx (waves 0 & 1 redundantly) ----
    u64 ownkey = 0;
    if (w <= 1) {
      u32 ord = 0;
      if (l < 32) {
        double a = 0.0;   // double final reduce: argmax robustness
#pragma unroll
        for (int k = 0; k < 32; k += 4) {
          float4 v = *(const float4*)&red[l * 36 + k];
          a += (double)v.x + (double)v.y + (double)v.z + (double)v.w;
        }
        a += (double)C_b[32 * b + l];
        float af = (float)a;
        u32 bits = __float_as_uint(af);
        ord = (bits & 0x80000000u) ? ~bits : (bits | 0x80000000u);
      }
      u32 maxord = wave_max_u32(ord);              // wave-uniform
      u64 mask = __ballot((int)(ord == maxord));   // lanes>=32 have ord=0 != maxord
      int lane = __builtin_ctzll(mask);            // smallest l -> smallest gidx
      u64 key41 = ((u64)maxord << 9) | (u64)(511 - (32 * b + lane));
      if (tid == 64)   // wave 1 lane 0: the only hot-path flagB store
        st_flag_rlx(&F[16 + (size_t)(t & 1) * 16 + b], ((u64)(t + 1) << 41) | key41);
      ownkey = key41;
    }

    // ---- produce gi(t+3) on waves 1-3 (barrier-free) while wave 0 polls ----
    if (w >= 1 && t + 3 < T_STEPS) produce_gi(t + 3);

    u32 info;
    if (w == 0) {
      // ---- poll 15 remote keys (own key in-register) ----
      u64 v = 0;
      int guard = 0;
      const bool need = (l < G) && (l != b);
      for (;;) {
        v = need ? ld_flag(&F[16 + (size_t)(t & 1) * 16 + l]) : 0;
        bool ok = !need || ((v >> 41) == (u64)(t + 1));
        if (__ballot((int)ok) == ~0ull) break;
        if (++guard > (1 << 22)) break;
      }
      u64 key = (l < G) ? ((l == b) ? ownkey : (v & ((1ull << 41) - 1))) : 0;
      // DPP argmax over 16 keys: max ord, then max low-bits among ties
      u32 o = (u32)(key >> 9);
      u32 maxo = row16_max_u32(o);
      u32 cand = (o == maxo && l < G) ? (u32)(key & 511u) : 0u;
      u32 best = row16_max_u32(cand);
      int q = 511 - (int)best;
      u32 vinfo = 0;
      if (l == 0) {
        u32 wr = written[q];
        u32 fresh = (q > 0 && wr == 0u) ? 1u : 0u;
        u32 rhit  = (q > 0 && wr != 0u) ? 1u : 0u;
        if (fresh) written[q] = 1u;
        vinfo = (u32)q | (fresh << 16) | (rhit << 17);
      }
      vinfo = (u32)__builtin_amdgcn_readfirstlane((int)vinfo);  // lane 0's value
      info = vinfo;
      if (l == 0)
        __hip_atomic_store(&bcw, (vinfo << 4) | ((u32)(t + 1) & 0xFu),
                           __ATOMIC_RELEASE, __HIP_MEMORY_SCOPE_WORKGROUP);
    } else {
      // ---- LDS epoch spin (no vmcnt dependency, no barrier) ----
      u32 v;
      int guard = 0;
      for (;;) {
        v = __hip_atomic_load(&bcw, __ATOMIC_ACQUIRE, __HIP_MEMORY_SCOPE_WORKGROUP);
        if ((v & 0xFu) == ((u32)(t + 1) & 0xFu)) break;
        if (++guard > (1 << 25)) break;
      }
      info = v >> 4;
    }
    int  q     = (int)(info & 0xFFFFu);
    bool fresh = (info >> 16) & 1u;
    bool rhit  = (info >> 17) & 1u;

    if (!rhit) {
      // h_out = h_new: emit H[t]; compute gh for next step (rare path)
      H[(size_t)t * 512 + tid]       = hnew[tid];
      H[(size_t)t * 512 + tid + 256] = hnew[tid + 256];
      float* dst;
      if (fresh) {
        if (tid < 32) st_cohf(&Mrow[(size_t)q * 512 + 32 * b + tid], hnew[32 * b + tid]);
        dst = &GH[(size_t)q * 1536];
      } else {
        dst = GHS;
      }
      compute_gh(dst);
      if (tid == 0) st_flag_rel(&F[48 + (size_t)(t & 1) * 16 + b], (u64)(t + 1));
      if (w == 0) {
        int guard = 0;
        for (;;) {
          u64 v = (l < G) ? ld_flag(&F[48 + (size_t)(t & 1) * 16 + l]) : 0;
          bool ok = (l >= G) || (v == (u64)(t + 1));
          if (__ballot((int)ok) == ~0ull) break;
          if (++guard > (1 << 22)) break;
        }
      }
      __syncthreads();
      ghsrc = dst;
      prevReadHit = false;
    } else {
      ghsrc = &GH[(size_t)q * 1536];
      prevReadHit = true;
      qprev = q;
    }
  }

  // epilogue: H[T-1] for trailing read-hit
  if (prevReadHit) {
    float a = ld_cohf(&Mrow[(size_t)qprev * 512 + tid]);
    float c = ld_cohf(&Mrow[(size_t)qprev * 512 + tid + 256]);
    H[(size_t)(T_STEPS - 1) * 512 + tid]       = a;
    H[(size_t)(T_STEPS - 1) * 512 + tid + 256] = c;
  }
}

// ---- V_w transpose ----
__global__ void vw_transpose(const float* __restrict__ Vw, float* __restrict__ VwT) {
  int idx = blockIdx.x * 256 + threadIdx.x;
  int kk = idx >> 8, ll = idx & 255;
  VwT[idx] = Vw[(size_t)ll * MDIM + kk];
}

// ---- Y = H @ V_w^T + V_b ----
__global__ __launch_bounds__(256) void y_gemm(const float* __restrict__ Hm,
                                              const float* __restrict__ VwT,
                                              const float* __restrict__ Vb,
                                              float* __restrict__ Y) {
  int t0 = blockIdx.x * 16;
  int tid = threadIdx.x;
  __shared__ __align__(16) float hs[16 * MDIM];
  for (int i = tid; i < 16 * MDIM; i += 256)
    hs[i] = Hm[(size_t)t0 * MDIM + i];
  __syncthreads();
  float acc[16];
  float vb = Vb[tid];
#pragma unroll
  for (int r = 0; r < 16; r++) acc[r] = vb;
  for (int k = 0; k < MDIM; k += 4) {
    float v0 = VwT[(size_t)(k + 0) * LOUT + tid];
    float v1 = VwT[(size_t)(k + 1) * LOUT + tid];
    float v2 = VwT[(size_t)(k + 2) * LOUT + tid];
    float v3 = VwT[(size_t)(k + 3) * LOUT + tid];
#pragma unroll
    for (int r = 0; r < 16; r++) {
      float4 h4 = *(const float4*)&hs[r * MDIM + k];
      acc[r] = fmaf(h4.x, v0, fmaf(h4.y, v1, fmaf(h4.z, v2, fmaf(h4.w, v3, acc[r]))));
    }
  }
#pragma unroll
  for (int r = 0; r < 16; r++)
    Y[(size_t)(t0 + r) * LOUT + tid] = acc[r];
}

extern "C" void kernel_launch(void* const* d_in, const int* in_sizes, int n_in,
                              void* d_out, int out_size, void* d_ws, size_t ws_size,
                              hipStream_t stream) {
  const float* X    = (const float*)d_in[0];
  const float* h0   = (const float*)d_in[1];
  const float* W_ih = (const float*)d_in[2];
  const float* W_hh = (const float*)d_in[3];
  const float* b_ih = (const float*)d_in[4];
  const float* b_hh = (const float*)d_in[5];
  const float* C_w  = (const float*)d_in[6];
  const float* C_b  = (const float*)d_in[7];
  const float* V_w  = (const float*)d_in[8];
  const float* V_b  = (const float*)d_in[9];
  float* ws  = (float*)d_ws;
  float* VwT = ws + OFF_VWT;
  float* Hm  = ws + OFF_H;

  hipLaunchKernelGGL(vw_transpose, dim3(512), dim3(256), 0, stream, V_w, VwT);
  hipLaunchKernelGGL(dmm_main, dim3(G), dim3(TPB), 0, stream,
                     X, h0, W_ih, W_hh, b_ih, b_hh, C_w, C_b, ws);
  hipLaunchKernelGGL(y_gemm, dim3(T_STEPS / 16), dim3(256), 0, stream,
                     Hm, VwT, V_b, (float*)d_out);
}

// Round 9
// 43963.895 us; speedup vs baseline: 1.6366x; 1.0238x over previous
//
#include <hip/hip_runtime.h>
#include <stdint.h>

#define T_STEPS 16384
#define NDIM 256
#define MDIM 512
#define KP1 512
#define LOUT 256
#define G 16
#define TPB 256

typedef unsigned long long u64;
typedef unsigned int u32;

// ---- ws layout (float offsets) ----
constexpr size_t OFF_GH    = 0;                         // [512][1536] cached W_hh@M[q]+b_hh
constexpr size_t OFF_GHS   = 512ull * 1536;             // [1536] scratch gh (q==0 / startup)
constexpr size_t OFF_M     = OFF_GHS + 1536;            // [512][512] memory rows
constexpr size_t OFF_RING  = OFF_M + 512ull * 512;      // [4][1536] gi ring
constexpr size_t OFF_H     = OFF_RING + 4ull * 1536;    // [16384][512] hidden outputs
constexpr size_t OFF_VWT   = OFF_H + 16384ull * 512;    // [512][256] V_w transposed
constexpr size_t OFF_FLAGS = OFF_VWT + 512ull * 256;    // u64 flags (compact layout)

__device__ __forceinline__ float ld_cohf(const float* p) {
  return __hip_atomic_load(p, __ATOMIC_RELAXED, __HIP_MEMORY_SCOPE_AGENT);
}
__device__ __forceinline__ void st_cohf(float* p, float v) {
  __hip_atomic_store(p, v, __ATOMIC_RELAXED, __HIP_MEMORY_SCOPE_AGENT);
}
__device__ __forceinline__ u64 ld_flag(const u64* p) {
  return __hip_atomic_load(p, __ATOMIC_RELAXED, __HIP_MEMORY_SCOPE_AGENT);
}
__device__ __forceinline__ void st_flag_rel(u64* p, u64 v) {
  __hip_atomic_store(p, v, __ATOMIC_RELEASE, __HIP_MEMORY_SCOPE_AGENT);
}
__device__ __forceinline__ void st_flag_rlx(u64* p, u64 v) {
  __hip_atomic_store(p, v, __ATOMIC_RELAXED, __HIP_MEMORY_SCOPE_AGENT);
}

__device__ __forceinline__ float sigm(float x) {
  return __builtin_amdgcn_rcpf(1.0f + __expf(-x));
}
__device__ __forceinline__ float tanh_(float x) {
  return 1.0f - 2.0f * __builtin_amdgcn_rcpf(__expf(2.0f * x) + 1.0f);
}

// ---- DPP max-reduce helpers (VALU-rate cross-lane, no ds_bpermute) ----
template<int CTRL>
__device__ __forceinline__ u32 dppmax(u32 v) {
  u32 t = (u32)__builtin_amdgcn_update_dpp(0, (int)v, CTRL, 0xf, 0xf, true);
  return v > t ? v : t;
}
__device__ __forceinline__ u32 wave_max_u32(u32 v) {
  v = dppmax<0x111>(v);   // row_shr:1
  v = dppmax<0x112>(v);   // row_shr:2
  v = dppmax<0x114>(v);   // row_shr:4
  v = dppmax<0x118>(v);   // row_shr:8
  v = dppmax<0x142>(v);   // row_bcast:15
  v = dppmax<0x143>(v);   // row_bcast:31
  return (u32)__builtin_amdgcn_readlane((int)v, 63);
}
__device__ __forceinline__ u32 row16_max_u32(u32 v) {
  v = dppmax<0x111>(v);
  v = dppmax<0x112>(v);
  v = dppmax<0x114>(v);
  v = dppmax<0x118>(v);
  return (u32)__builtin_amdgcn_readlane((int)v, 15);
}

__global__ __launch_bounds__(TPB, 1) void dmm_main(
    const float* __restrict__ X, const float* __restrict__ h0,
    const float* __restrict__ W_ih, const float* __restrict__ W_hh,
    const float* __restrict__ b_ih, const float* __restrict__ b_hh,
    const float* __restrict__ C_w, const float* __restrict__ C_b,
    float* __restrict__ ws)
{
  const int b   = blockIdx.x;
  const int tid = threadIdx.x;
  const int w   = tid >> 6;
  const int l   = tid & 63;

  float* GH   = ws + OFF_GH;
  float* GHS  = ws + OFF_GHS;
  float* Mrow = ws + OFF_M;
  float* RING = ws + OFF_RING;
  float* H    = ws + OFF_H;
  u64*   F    = (u64*)(ws + OFF_FLAGS);
  // flagS = F[0..15], flagB = F[16 + p*16 + b], flagC = F[48 + p*16 + b]

  __shared__ __align__(16) float hnew[MDIM];
  __shared__ __align__(16) float red[96 * 36];   // logits reduce + gh reduce (rare path)
  __shared__ u32 written[KP1];
  __shared__ u32 bcw;                            // (info<<4) | epoch4

  // ---- persistent register-resident weight slices ----
  const int pw   = (w >= 1) ? (w - 1) : 0;
  const int rloc = pw * 32 + (l >> 4) * 8;        // local row base 0..95 (waves 1-3)
  float wih[8][16];
  {
    int rbase = 96 * b + rloc;
    int cbase = 16 * (l & 15);
#pragma unroll
    for (int i = 0; i < 8; i++)
#pragma unroll
      for (int k = 0; k < 16; k++)
        wih[i][k] = W_ih[(size_t)(rbase + i) * NDIM + cbase + k];
  }
  float bihr[8];
#pragma unroll
  for (int i = 0; i < 8; i++) bihr[i] = b_ih[96 * b + rloc + i];

  float cw[4][16];
  {
    int rbase = 32 * b + w * 8 + (l >> 5) * 4;
    int cbase = 16 * (l & 31);
#pragma unroll
    for (int i = 0; i < 4; i++)
#pragma unroll
      for (int k = 0; k < 16; k++)
        cw[i][k] = C_w[(size_t)(rbase + i) * MDIM + cbase + k];
  }

  for (int i = tid; i < KP1; i += TPB) written[i] = 0u;
  if (tid == 0) bcw = 0u;
  hnew[tid]       = h0[tid];
  hnew[tid + 256] = h0[tid + 256];
  __syncthreads();

  // ---- X register prefetch (waves 1-3): xreg holds X(s) for the next produce ----
  float xreg[16];
  auto prefetchX = [&](int s) {
    int cbase = 16 * (l & 15);
#pragma unroll
    for (int k = 0; k < 16; k++) xreg[k] = X[(size_t)s * NDIM + cbase + k];
  };

  // ---- produce gi(s) from prefetched xreg: shfl-only, barrier-free; waves 1..3 ----
  auto produce_gi = [&](int s) {
    float p[8];
#pragma unroll
    for (int i = 0; i < 8; i++) {
      float a = 0.f;
#pragma unroll
      for (int k = 0; k < 16; k++) a = fmaf(wih[i][k], xreg[k], a);
      p[i] = a;
    }
#pragma unroll
    for (int off = 1; off <= 8; off <<= 1) {
#pragma unroll
      for (int i = 0; i < 8; i++) p[i] += __shfl_xor(p[i], off, 64);
    }
    if ((l & 15) == 0) {
      float* dst = &RING[(size_t)(s & 3) * 1536 + 96 * b + rloc];
#pragma unroll
      for (int i = 0; i < 8; i++) st_cohf(&dst[i], p[i] + bihr[i]);
    }
  };

  auto compute_gh = [&](float* dst) {
    int cb = 16 * (l & 31);
    float hr[16];
#pragma unroll
    for (int k = 0; k < 16; k += 4) *(float4*)&hr[k] = *(const float4*)&hnew[cb + k];
    int rb = 96 * b + w * 24 + (l >> 5) * 12;
    float p[12];
#pragma unroll
    for (int i = 0; i < 12; i++) {
      float a = 0.f;
      const float* wr = &W_hh[(size_t)(rb + i) * MDIM + cb];
#pragma unroll
      for (int k = 0; k < 16; k++) a = fmaf(wr[k], hr[k], a);
      p[i] = a;
    }
    int rl = w * 24 + (l >> 5) * 12;
    int lc = l & 31;
#pragma unroll
    for (int i = 0; i < 12; i++) red[(rl + i) * 36 + lc] = p[i];
    __syncthreads();
    if (tid < 96) {
      float a = 0.f;
#pragma unroll
      for (int k = 0; k < 32; k += 4) {
        float4 v = *(const float4*)&red[tid * 36 + k];
        a += v.x + v.y + v.z + v.w;
      }
      a += b_hh[96 * b + tid];
      st_cohf(&dst[96 * b + tid], a);
    }
    __syncthreads();
  };

  // ---- startup: gi(0..2) by waves 1-3 (prefetch-feed), gh(h0) ----
  if (w >= 1) {
    prefetchX(0); produce_gi(0);
    prefetchX(1); produce_gi(1);
    prefetchX(2); produce_gi(2);
    prefetchX(3);                       // xreg invariant: holds X(t+3) at step t
  }
  __syncthreads();
  compute_gh(GHS);
  if (tid == 0) st_flag_rel(&F[b], 1ull);
  if (w == 0) {
    int guard = 0;
    bool done = false;
    while (!done) {
      u64 v = (l < G) ? ld_flag(&F[l]) : 1ull;
      done = (__ballot((int)(v == 1ull)) == ~0ull);
      if (++guard > (1 << 22)) break;
    }
  }
  __syncthreads();

  const float* ghsrc = GHS;
  bool prevReadHit = false;
  int  qprev = 0;

  for (int t = 0; t < T_STEPS; ++t) {
    // ---- issue all dependent sc1 loads up front ----
    float g0 = ld_cohf(&ghsrc[tid]);
    float g1 = ld_cohf(&ghsrc[tid + 256]);
    float g2 = ld_cohf(&ghsrc[512 + tid]);
    float g3 = ld_cohf(&ghsrc[512 + tid + 256]);
    float g4 = ld_cohf(&ghsrc[1024 + tid]);
    float g5 = ld_cohf(&ghsrc[1024 + tid + 256]);
    float m0 = 0.f, m1 = 0.f;
    if (prevReadHit) {
      m0 = ld_cohf(&Mrow[(size_t)qprev * 512 + tid]);
      m1 = ld_cohf(&Mrow[(size_t)qprev * 512 + tid + 256]);
    }
    const float* gi = &RING[(size_t)(t & 3) * 1536];
    float i0 = ld_cohf(&gi[tid]);
    float i1 = ld_cohf(&gi[tid + 256]);
    float i2 = ld_cohf(&gi[512 + tid]);
    float i3 = ld_cohf(&gi[512 + tid + 256]);
    float i4 = ld_cohf(&gi[1024 + tid]);
    float i5 = ld_cohf(&gi[1024 + tid + 256]);

    // lagged H write for read-hit step t-1 (plain store: fast L2 ack)
    if (prevReadHit) {
      H[(size_t)(t - 1) * 512 + tid]       = m0;
      H[(size_t)(t - 1) * 512 + tid + 256] = m1;
    }

    // ---- gates (torch GRU semantics) ----
    float hp0 = prevReadHit ? m0 : hnew[tid];
    float hp1 = prevReadHit ? m1 : hnew[tid + 256];
    float r0 = sigm(i0 + g0), r1 = sigm(i1 + g1);
    float z0 = sigm(i2 + g2), z1 = sigm(i3 + g3);
    float n0 = tanh_(fmaf(r0, g4, i4)), n1 = tanh_(fmaf(r1, g5, i5));
    float hn0 = fmaf(z0, hp0 - n0, n0);
    float hn1 = fmaf(z1, hp1 - n1, n1);
    hnew[tid]       = hn0;
    hnew[tid + 256] = hn1;
    __syncthreads();                               // B1

    // ---- logits slice (32 rows) from register-resident C_w ----
    {
      int cb = 16 * (l & 31);
      float hr[16];
#pragma unroll
      for (int k = 0; k < 16; k += 4) *(float4*)&hr[k] = *(const float4*)&hnew[cb + k];
      float p0 = 0.f, p1 = 0.f, p2 = 0.f, p3 = 0.f;
#pragma unroll
      for (int k = 0; k < 16; k++) {
        p0 = fmaf(cw[0][k], hr[k], p0);
        p1 = fmaf(cw[1][k], hr[k], p1);
        p2 = fmaf(cw[2][k], hr[k], p2);
        p3 = fmaf(cw[3][k], hr[k], p3);
      }
      int rl = w * 8 + (l >> 5) * 4;
      int lc = l & 31;
      red[(rl + 0) * 36 + lc] = p0;
      red[(rl + 1) * 36 + lc] = p1;
      red[(rl + 2) * 36 + lc] = p2;
      red[(rl + 3) * 36 + lc] = p3;
    }
    __syncthreads();                               // B2

    // ---- block key: tree-double reduce + DPP max (waves 0 & 1 redundantly) ----
    u64 ownkey = 0;
    if (w <= 1) {
      u32 ord = 0;
      if (l < 32) {
        const float4* rp = (const float4*)&red[l * 36];
        float4 v0 = rp[0], v1 = rp[1], v2 = rp[2], v3 = rp[3];
        float4 v4 = rp[4], v5 = rp[5], v6 = rp[6], v7 = rp[7];
        // deterministic fixed-shape tree (identical on waves 0 and 1)
        double d0 = ((double)v0.x + (double)v0.y) + ((double)v0.z + (double)v0.w);
        double d1 = ((double)v1.x + (double)v1.y) + ((double)v1.z + (double)v1.w);
        double d2 = ((double)v2.x + (double)v2.y) + ((double)v2.z + (double)v2.w);
        double d3 = ((double)v3.x + (double)v3.y) + ((double)v3.z + (double)v3.w);
        double d4 = ((double)v4.x + (double)v4.y) + ((double)v4.z + (double)v4.w);
        double d5 = ((double)v5.x + (double)v5.y) + ((double)v5.z + (double)v5.w);
        double d6 = ((double)v6.x + (double)v6.y) + ((double)v6.z + (double)v6.w);
        double d7 = ((double)v7.x + (double)v7.y) + ((double)v7.z + (double)v7.w);
        double a = (((d0 + d1) + (d2 + d3)) + ((d4 + d5) + (d6 + d7)))
                 + (double)C_b[32 * b + l];
        float af = (float)a;
        u32 bits = __float_as_uint(af);
        ord = (bits & 0x80000000u) ? ~bits : (bits | 0x80000000u);
      }
      u32 maxord = wave_max_u32(ord);              // wave-uniform
      u64 mask = __ballot((int)(ord == maxord));   // lanes>=32 have ord=0 != maxord
      int lane = __builtin_ctzll(mask);            // smallest l -> smallest gidx
      u64 key41 = ((u64)maxord << 9) | (u64)(511 - (32 * b + lane));
      if (tid == 64)   // wave 1 lane 0: the only hot-path flagB store
        st_flag_rlx(&F[16 + (size_t)(t & 1) * 16 + b], ((u64)(t + 1) << 41) | key41);
      ownkey = key41;
    }

    // ---- produce gi(t+3) from xreg, then prefetch X(t+4) (waves 1-3) ----
    if (w >= 1 && t + 3 < T_STEPS) {
      produce_gi(t + 3);
      if (t + 4 < T_STEPS) prefetchX(t + 4);
    }

    u32 info;
    if (w == 0) {
      // ---- pipelined poll: one flag-load always in flight ----
      const bool need = (l < G) && (l != b);
      const u64* fp = &F[16 + (size_t)(t & 1) * 16 + l];
      u64 vp = need ? ld_flag(fp) : 0;
      int guard = 0;
      u64 v;
      for (;;) {
        u64 vn = need ? ld_flag(fp) : 0;       // issue next before checking prev
        bool ok = !need || ((vp >> 41) == (u64)(t + 1));
        if (__ballot((int)ok) == ~0ull) { v = vp; break; }
        vp = vn;
        if (++guard > (1 << 22)) { v = vp; break; }
      }
      u64 key = (l < G) ? ((l == b) ? ownkey : (v & ((1ull << 41) - 1))) : 0;
      // DPP argmax over 16 keys: max ord, then max low-bits among ties
      u32 o = (u32)(key >> 9);
      u32 maxo = row16_max_u32(o);
      u32 cand = (o == maxo && l < G) ? (u32)(key & 511u) : 0u;
      u32 best = row16_max_u32(cand);
      int q = 511 - (int)best;
      u32 vinfo = 0;
      if (l == 0) {
        u32 wr = written[q];
        u32 fresh = (q > 0 && wr == 0u) ? 1u : 0u;
        u32 rhit  = (q > 0 && wr != 0u) ? 1u : 0u;
        if (fresh) written[q] = 1u;
        vinfo = (u32)q | (fresh << 16) | (rhit << 17);
      }
      vinfo = (u32)__builtin_amdgcn_readfirstlane((int)vinfo);  // lane 0's value
      info = vinfo;
      if (l == 0)
        __hip_atomic_store(&bcw, (vinfo << 4) | ((u32)(t + 1) & 0xFu),
                           __ATOMIC_RELEASE, __HIP_MEMORY_SCOPE_WORKGROUP);
    } else {
      // ---- LDS epoch spin (no vmcnt dependency, no barrier) ----
      u32 v;
      int guard = 0;
      for (;;) {
        v = __hip_atomic_load(&bcw, __ATOMIC_ACQUIRE, __HIP_MEMORY_SCOPE_WORKGROUP);
        if ((v & 0xFu) == ((u32)(t + 1) & 0xFu)) break;
        if (++guard > (1 << 25)) break;
      }
      info = v >> 4;
    }
    int  q     = (int)(info & 0xFFFFu);
    bool fresh = (info >> 16) & 1u;
    bool rhit  = (info >> 17) & 1u;

    if (!rhit) {
      // h_out = h_new: emit H[t]; compute gh for next step (rare path)
      H[(size_t)t * 512 + tid]       = hnew[tid];
      H[(size_t)t * 512 + tid + 256] = hnew[tid + 256];
      float* dst;
      if (fresh) {
        if (tid < 32) st_cohf(&Mrow[(size_t)q * 512 + 32 * b + tid], hnew[32 * b + tid]);
        dst = &GH[(size_t)q * 1536];
      } else {
        dst = GHS;
      }
      compute_gh(dst);
      if (tid == 0) st_flag_rel(&F[48 + (size_t)(t & 1) * 16 + b], (u64)(t + 1));
      if (w == 0) {
        int guard = 0;
        for (;;) {
          u64 v = (l < G) ? ld_flag(&F[48 + (size_t)(t & 1) * 16 + l]) : 0;
          bool ok = (l >= G) || (v == (u64)(t + 1));
          if (__ballot((int)ok) == ~0ull) break;
          if (++guard > (1 << 22)) break;
        }
      }
      __syncthreads();
      ghsrc = dst;
      prevReadHit = false;
    } else {
      ghsrc = &GH[(size_t)q * 1536];
      prevReadHit = true;
      qprev = q;
    }
  }

  // epilogue: H[T-1] for trailing read-hit
  if (prevReadHit) {
    float a = ld_cohf(&Mrow[(size_t)qprev * 512 + tid]);
    float c = ld_cohf(&Mrow[(size_t)qprev * 512 + tid + 256]);
    H[(size_t)(T_STEPS - 1) * 512 + tid]       = a;
    H[(size_t)(T_STEPS - 1) * 512 + tid + 256] = c;
  }
}

// ---- V_w transpose ----
__global__ void vw_transpose(const float* __restrict__ Vw, float* __restrict__ VwT) {
  int idx = blockIdx.x * 256 + threadIdx.x;
  int kk = idx >> 8, ll = idx & 255;
  VwT[idx] = Vw[(size_t)ll * MDIM + kk];
}

// ---- Y = H @ V_w^T + V_b ----
__global__ __launch_bounds__(256) void y_gemm(const float* __restrict__ Hm,
                                              const float* __restrict__ VwT,
                                              const float* __restrict__ Vb,
                                              float* __restrict__ Y) {
  int t0 = blockIdx.x * 16;
  int tid = threadIdx.x;
  __shared__ __align__(16) float hs[16 * MDIM];
  for (int i = tid; i < 16 * MDIM; i += 256)
    hs[i] = Hm[(size_t)t0 * MDIM + i];
  __syncthreads();
  float acc[16];
  float vb = Vb[tid];
#pragma unroll
  for (int r = 0; r < 16; r++) acc[r] = vb;
  for (int k = 0; k < MDIM; k += 4) {
    float v0 = VwT[(size_t)(k + 0) * LOUT + tid];
    float v1 = VwT[(size_t)(k + 1) * LOUT + tid];
    float v2 = VwT[(size_t)(k + 2) * LOUT + tid];
    float v3 = VwT[(size_t)(k + 3) * LOUT + tid];
#pragma unroll
    for (int r = 0; r < 16; r++) {
      float4 h4 = *(const float4*)&hs[r * MDIM + k];
      acc[r] = fmaf(h4.x, v0, fmaf(h4.y, v1, fmaf(h4.z, v2, fmaf(h4.w, v3, acc[r]))));
    }
  }
#pragma unroll
  for (int r = 0; r < 16; r++)
    Y[(size_t)(t0 + r) * LOUT + tid] = acc[r];
}

extern "C" void kernel_launch(void* const* d_in, const int* in_sizes, int n_in,
                              void* d_out, int out_size, void* d_ws, size_t ws_size,
                              hipStream_t stream) {
  const float* X    = (const float*)d_in[0];
  const float* h0   = (const float*)d_in[1];
  const float* W_ih = (const float*)d_in[2];
  const float* W_hh = (const float*)d_in[3];
  const float* b_ih = (const float*)d_in[4];
  const float* b_hh = (const float*)d_in[5];
  const float* C_w  = (const float*)d_in[6];
  const float* C_b  = (const float*)d_in[7];
  const float* V_w  = (const float*)d_in[8];
  const float* V_b  = (const float*)d_in[9];
  float* ws  = (float*)d_ws;
  float* VwT = ws + OFF_VWT;
  float* Hm  = ws + OFF_H;

  hipLaunchKernelGGL(vw_transpose, dim3(512), dim3(256), 0, stream, V_w, VwT);
  hipLaunchKernelGGL(dmm_main, dim3(G), dim3(TPB), 0, stream,
                     X, h0, W_ih, W_hh, b_ih, b_hh, C_w, C_b, ws);
  hipLaunchKernelGGL(y_gemm, dim3(T_STEPS / 16), dim3(256), 0, stream,
                     Hm, VwT, V_b, (float*)d_out);
}